// Round 2
// baseline (46661.960 us; speedup 1.0000x reference)
//
#include <hip/hip_runtime.h>
#include <cstdint>
#include <cstddef>

#define B_    256
#define T_    1024
#define NDYN  20
#define DH    64
#define DZ    128
#define HIDN  64
#define GCOLS 384   // 3*DZ
#define XDIM  104   // 2*NDYN + DH

// chunk-padded LDS index: 16-float chunks at stride 20 (conflict-free float4 reads)
__device__ __forceinline__ int cpad(int k) { return (k >> 4) * 20 + (k & 15); }

// DPP cross-lane add (VALU pipe, not LDS). CTRL: 0xB1=quad_perm(1,0,3,2) ~ xor1,
// 0x4E=quad_perm(2,3,0,1) ~ xor2, 0x141=row_half_mirror ~ xor4 (valid once quads uniform).
template<int CTRL, int XORMASK>
__device__ __forceinline__ float dpp_sum(float v) {
#if __has_builtin(__builtin_amdgcn_mov_dpp)
  int o = __builtin_amdgcn_mov_dpp(__float_as_int(v), CTRL, 0xF, 0xF, true);
  return v + __int_as_float(o);
#else
  return v + __shfl_xor(v, XORMASK);
#endif
}

__device__ __forceinline__ float tanh_fast(float x) {
  float a = __expf(-2.f * fabsf(x));
  return copysignf((1.f - a) / (1.f + a), x);
}
__device__ __forceinline__ float sigm(float x) { return 1.f / (1.f + __expf(-x)); }

// ---- AGPR residency for Whh ------------------------------------------------
// Two rounds of evidence: the backend pins this kernel at 128 arch VGPRs no
// matter what launch_bounds / waves_per_eu say, so the 192-float register
// working set spilled ~26 dwords/thread/step to scratch (10+ GB HBM traffic,
// 88% stall). Fix: place whh[128] (2/3 of the demand) in the OTHER half of the
// gfx950 unified register file — AGPRs — via v_accvgpr_write/read with "a"
// constraints. Remaining arch demand (wA+wB+temps ~110) fits 128 natively.
// Per-wave total 128 arch + 128 acc = 256 -> 2 waves/SIMD, schedulable for the
// 6-wave block. Reads are `asm volatile` so LICM cannot hoist all 128 back
// into VGPRs (which would recreate the spill pressure).
#define REP128(M) \
  M(0) M(1) M(2) M(3) M(4) M(5) M(6) M(7) \
  M(8) M(9) M(10) M(11) M(12) M(13) M(14) M(15) \
  M(16) M(17) M(18) M(19) M(20) M(21) M(22) M(23) \
  M(24) M(25) M(26) M(27) M(28) M(29) M(30) M(31) \
  M(32) M(33) M(34) M(35) M(36) M(37) M(38) M(39) \
  M(40) M(41) M(42) M(43) M(44) M(45) M(46) M(47) \
  M(48) M(49) M(50) M(51) M(52) M(53) M(54) M(55) \
  M(56) M(57) M(58) M(59) M(60) M(61) M(62) M(63) \
  M(64) M(65) M(66) M(67) M(68) M(69) M(70) M(71) \
  M(72) M(73) M(74) M(75) M(76) M(77) M(78) M(79) \
  M(80) M(81) M(82) M(83) M(84) M(85) M(86) M(87) \
  M(88) M(89) M(90) M(91) M(92) M(93) M(94) M(95) \
  M(96) M(97) M(98) M(99) M(100) M(101) M(102) M(103) \
  M(104) M(105) M(106) M(107) M(108) M(109) M(110) M(111) \
  M(112) M(113) M(114) M(115) M(116) M(117) M(118) M(119) \
  M(120) M(121) M(122) M(123) M(124) M(125) M(126) M(127)

#define AGD(K) float ag##K;
#define AGLD(K) { float v_ = Whh[(K) * GCOLS + tid]; \
  asm volatile("v_accvgpr_write_b32 %0, %1" : "=a"(ag##K) : "v"(v_)); }
#define AGR(K, W) asm volatile("v_accvgpr_read_b32 %0, %1" : "=v"(W) : "a"(ag##K));
#define GRUQ(ACC, ZV, K0, K1, K2, K3) { float w0_, w1_, w2_, w3_; \
  AGR(K0, w0_) AGR(K1, w1_) AGR(K2, w2_) AGR(K3, w3_) \
  ACC += w0_ * ZV.x + w1_ * ZV.y + w2_ * ZV.z + w3_ * ZV.w; }

__global__
__attribute__((amdgpu_flat_work_group_size(384, 384)))
__attribute__((amdgpu_waves_per_eu(2, 2)))
void odernn_kernel(
    const float* __restrict__ z0, const float* __restrict__ tdyn,
    const float* __restrict__ Y, const float* __restrict__ Mm,
    const float* __restrict__ Hh, const int* __restrict__ lens,
    const float* __restrict__ W0, const float* __restrict__ b0,
    const float* __restrict__ W1, const float* __restrict__ b1,
    const float* __restrict__ W2, const float* __restrict__ b2,
    const float* __restrict__ Wih, const float* __restrict__ bih,
    const float* __restrict__ Whh, const float* __restrict__ bhh,
    const float* __restrict__ gi_pre, float* __restrict__ out, int use_gi)
{
  const int tid = threadIdx.x;
  const int b   = blockIdx.x;

  __shared__ __align__(16) float vinP[160];   // RK4 input v, 8 chunks of 16 @ stride 20
  __shared__ __align__(16) float h1P[80];     // 4 chunks
  __shared__ __align__(16) float h2P[80];     // 4 chunks
  __shared__ __align__(16) float zodeL[128];  // flat, float4-broadcast in GRU
  __shared__ float zcurL[128];
  __shared__ float gateL[384];
  __shared__ float gateN[128];
  __shared__ float xsL[112];

  // Register-resident weights:
  //   ag0..ag127 (AGPRs): GRU column tid of Whh
  //   wA[32] (VGPR): tid<256 -> L0 slice ; tid>=256 -> L2 slice
  //   wB[32] (VGPR): tid<128 -> L1 slice ; 128<=tid<256 -> L2 slice
  float wA[32], wB[32];
  REP128(AGD)

  REP128(AGLD)

  if (tid < 256) {            // L0: jg=tid>>3 (2 outputs), p=tid&7 (K-chunk of 16)
    const int jg = tid >> 3, p = tid & 7, j0 = 2 * jg, kb = 16 * p;
    #pragma unroll
    for (int i = 0; i < 16; ++i) {
      wA[i]      = W0[(kb + i) * HIDN + j0];
      wA[16 + i] = W0[(kb + i) * HIDN + j0 + 1];
    }
  } else {                    // L2 (upper half of thread slots)
    const int u = tid - 128, jg = u >> 2, p = u & 3, j0 = 2 * jg, kb = 16 * p;
    #pragma unroll
    for (int i = 0; i < 16; ++i) {
      wA[i]      = W2[(kb + i) * DZ + j0];
      wA[16 + i] = W2[(kb + i) * DZ + j0 + 1];
    }
  }
  if (tid < 128) {            // L1: jg=tid>>2, p=tid&3
    const int jg = tid >> 2, p = tid & 3, j0 = 2 * jg, kb = 16 * p;
    #pragma unroll
    for (int i = 0; i < 16; ++i) {
      wB[i]      = W1[(kb + i) * HIDN + j0];
      wB[16 + i] = W1[(kb + i) * HIDN + j0 + 1];
    }
  } else if (tid < 256) {     // L2 (lower half of thread slots)
    const int u = tid - 128, jg = u >> 2, p = u & 3, j0 = 2 * jg, kb = 16 * p;
    #pragma unroll
    for (int i = 0; i < 16; ++i) {
      wB[i]      = W2[(kb + i) * DZ + j0];
      wB[16 + i] = W2[(kb + i) * DZ + j0 + 1];
    }
  }

  float b0r = 0.f, b1r = 0.f, b2r = 0.f;
  if (tid < 256 && (tid & 7) < 2) b0r = b0[2 * (tid >> 3) + (tid & 7)];
  if (tid < 128 && (tid & 3) < 2) b1r = b1[2 * (tid >> 2) + (tid & 3)];
  if (tid >= 128 && ((tid - 128) & 3) < 2)
    b2r = b2[2 * ((tid - 128) >> 2) + ((tid - 128) & 3)];
  const float bhhr = bhh[tid];
  const float bihr = bih[tid];
  const int   lenb = lens[b];

  if (tid < 128) {
    float zv = z0[(size_t)b * DZ + tid];
    vinP[cpad(tid)] = zv;
    zcurL[tid] = zv;
  }
  __syncthreads();

  float* Zbase = out + (size_t)B_ * DZ;
  const float* tdb = tdyn + (size_t)b * T_;

  const int u2 = tid - 128, jg2 = u2 >> 2, p2 = u2 & 3;  // L2 role (valid tid>=128)
  const int j2 = 2 * jg2 + p2;                           // L2 writer output (p2<2)

  #pragma unroll 1
  for (int t = 0; t < T_; ++t) {
    const size_t bt = (size_t)b * T_ + t;
    // dt computed per-thread from global tdyn (no serializing LDS scalar):
    // t==0 -> dt = 0 exactly (matches reference's t_prev init = t_dyn[:,0]).
    const float dt = (t == 0) ? 0.f : fmaxf(tdb[t] - tdb[t - 1], 0.f);

    float gival = 0.f;
    if (use_gi) {
      gival = gi_pre[bt * GCOLS + tid];   // prefetch; consumed ~500 cyc later
    } else if (tid < XDIM) {
      float v;
      if (tid < 20)      v = Y[bt * NDYN + tid];
      else if (tid < 40) v = Mm[bt * NDYN + (tid - 20)];
      else               v = Hh[bt * DH + (tid - 40)];
      xsL[tid] = v;
    }

    float zreg = 0.f, kacc = 0.f;
    if (tid >= 128 && p2 < 2) zreg = zcurL[j2];

    // rolled (not unrolled): 4 RK stages are barrier-serialized anyway; rolling
    // shrinks live ranges / scheduling windows -> keeps arch VGPRs under 128.
    #pragma unroll 1
    for (int e = 0; e < 4; ++e) {
      // ---- L0: 64 outs, K=128 ---- (threads 0..255, group of 8, 2 outs each)
      if (tid < 256) {
        const int p = tid & 7, jg = tid >> 3;
        const float4* vp = (const float4*)&vinP[p * 20];
        float a0 = 0.f, a1 = 0.f;
        #pragma unroll
        for (int q = 0; q < 4; ++q) {
          float4 v = vp[q];
          a0 += wA[4*q+0]*v.x + wA[4*q+1]*v.y + wA[4*q+2]*v.z + wA[4*q+3]*v.w;
          a1 += wA[16+4*q+0]*v.x + wA[16+4*q+1]*v.y + wA[16+4*q+2]*v.z + wA[16+4*q+3]*v.w;
        }
        a0 = dpp_sum<0xB1,1>(a0); a0 = dpp_sum<0x4E,2>(a0); a0 = dpp_sum<0x141,4>(a0);
        a1 = dpp_sum<0xB1,1>(a1); a1 = dpp_sum<0x4E,2>(a1); a1 = dpp_sum<0x141,4>(a1);
        if (p < 2)
          h1P[cpad(2 * jg + p)] = tanh_fast((p ? a1 : a0) + b0r);
      }
      __syncthreads();
      // ---- L1: 64 outs, K=64 ---- (threads 0..127, group of 4)
      if (tid < 128) {
        const int p = tid & 3, jg = tid >> 2;
        const float4* hp = (const float4*)&h1P[p * 20];
        float a0 = 0.f, a1 = 0.f;
        #pragma unroll
        for (int q = 0; q < 4; ++q) {
          float4 v = hp[q];
          a0 += wB[4*q+0]*v.x + wB[4*q+1]*v.y + wB[4*q+2]*v.z + wB[4*q+3]*v.w;
          a1 += wB[16+4*q+0]*v.x + wB[16+4*q+1]*v.y + wB[16+4*q+2]*v.z + wB[16+4*q+3]*v.w;
        }
        a0 = dpp_sum<0xB1,1>(a0); a0 = dpp_sum<0x4E,2>(a0);
        a1 = dpp_sum<0xB1,1>(a1); a1 = dpp_sum<0x4E,2>(a1);
        if (p < 2)
          h2P[cpad(2 * jg + p)] = tanh_fast((p ? a1 : a0) + b1r);
      }
      __syncthreads();
      // ---- L2: 128 outs, K=64 ---- (threads 128..383, group of 4)
      if (tid >= 128) {
        const float4* hp = (const float4*)&h2P[p2 * 20];
        float a0 = 0.f, a1 = 0.f;
        if (tid < 256) {
          #pragma unroll
          for (int q = 0; q < 4; ++q) {
            float4 v = hp[q];
            a0 += wB[4*q+0]*v.x + wB[4*q+1]*v.y + wB[4*q+2]*v.z + wB[4*q+3]*v.w;
            a1 += wB[16+4*q+0]*v.x + wB[16+4*q+1]*v.y + wB[16+4*q+2]*v.z + wB[16+4*q+3]*v.w;
          }
        } else {
          #pragma unroll
          for (int q = 0; q < 4; ++q) {
            float4 v = hp[q];
            a0 += wA[4*q+0]*v.x + wA[4*q+1]*v.y + wA[4*q+2]*v.z + wA[4*q+3]*v.w;
            a1 += wA[16+4*q+0]*v.x + wA[16+4*q+1]*v.y + wA[16+4*q+2]*v.z + wA[16+4*q+3]*v.w;
          }
        }
        a0 = dpp_sum<0xB1,1>(a0); a0 = dpp_sum<0x4E,2>(a0);
        a1 = dpp_sum<0xB1,1>(a1); a1 = dpp_sum<0x4E,2>(a1);
        if (p2 < 2) {
          const float kv = dt * ((p2 ? a1 : a0) + b2r);
          if (e == 0)      kacc = kv;
          else if (e == 3) kacc += kv;
          else             kacc += 2.f * kv;
          if (e < 3) {
            const float a = (e == 2) ? 1.f : 0.5f;
            vinP[cpad(j2)] = zreg + a * kv;
          } else {
            zodeL[j2] = zreg + kacc * (1.f / 6.f);
          }
        }
      }
      __syncthreads();
    }

    // ---- GRU: column tid. Whh column lives in AGPRs; LDS z reads batched 8x
    // b128 ahead of the volatile accvgpr reads so LDS latency pipelines. ----
    {
      float gh0 = 0.f, gh1 = 0.f, gh2 = 0.f, gh3 = 0.f;
      const float4* zp = (const float4*)zodeL;
      {
        float4 za = zp[0], zb = zp[1], zc = zp[2], zd = zp[3],
               ze = zp[4], zf = zp[5], zg = zp[6], zh = zp[7];
        GRUQ(gh0, za, 0,1,2,3)     GRUQ(gh1, zb, 4,5,6,7)
        GRUQ(gh2, zc, 8,9,10,11)   GRUQ(gh3, zd, 12,13,14,15)
        GRUQ(gh0, ze, 16,17,18,19) GRUQ(gh1, zf, 20,21,22,23)
        GRUQ(gh2, zg, 24,25,26,27) GRUQ(gh3, zh, 28,29,30,31)
      }
      {
        float4 za = zp[8], zb = zp[9], zc = zp[10], zd = zp[11],
               ze = zp[12], zf = zp[13], zg = zp[14], zh = zp[15];
        GRUQ(gh0, za, 32,33,34,35) GRUQ(gh1, zb, 36,37,38,39)
        GRUQ(gh2, zc, 40,41,42,43) GRUQ(gh3, zd, 44,45,46,47)
        GRUQ(gh0, ze, 48,49,50,51) GRUQ(gh1, zf, 52,53,54,55)
        GRUQ(gh2, zg, 56,57,58,59) GRUQ(gh3, zh, 60,61,62,63)
      }
      {
        float4 za = zp[16], zb = zp[17], zc = zp[18], zd = zp[19],
               ze = zp[20], zf = zp[21], zg = zp[22], zh = zp[23];
        GRUQ(gh0, za, 64,65,66,67) GRUQ(gh1, zb, 68,69,70,71)
        GRUQ(gh2, zc, 72,73,74,75) GRUQ(gh3, zd, 76,77,78,79)
        GRUQ(gh0, ze, 80,81,82,83) GRUQ(gh1, zf, 84,85,86,87)
        GRUQ(gh2, zg, 88,89,90,91) GRUQ(gh3, zh, 92,93,94,95)
      }
      {
        float4 za = zp[24], zb = zp[25], zc = zp[26], zd = zp[27],
               ze = zp[28], zf = zp[29], zg = zp[30], zh = zp[31];
        GRUQ(gh0, za, 96,97,98,99)     GRUQ(gh1, zb, 100,101,102,103)
        GRUQ(gh2, zc, 104,105,106,107) GRUQ(gh3, zd, 108,109,110,111)
        GRUQ(gh0, ze, 112,113,114,115) GRUQ(gh1, zf, 116,117,118,119)
        GRUQ(gh2, zg, 120,121,122,123) GRUQ(gh3, zh, 124,125,126,127)
      }
      float gh = bhhr + ((gh0 + gh1) + (gh2 + gh3));
      float gi;
      if (use_gi) gi = gival;
      else {
        gi = bihr;
        for (int i = 0; i < XDIM; ++i) gi += xsL[i] * Wih[(size_t)i * GCOLS + tid];
      }
      if (tid < 256) gateL[tid] = gi + gh;
      else { gateL[tid] = gh; gateN[tid - 256] = gi; }
    }
    __syncthreads();

    if (tid < 128) {
      const float r  = sigm(gateL[tid]);
      const float uu = sigm(gateL[128 + tid]);
      const float n  = tanh_fast(gateN[tid] + r * gateL[256 + tid]);
      const float zo = zodeL[tid];
      const float zn = (1.f - uu) * n + uu * zo;
      const float znew = (t < lenb) ? zn : zo;
      vinP[cpad(tid)] = znew;
      zcurL[tid] = znew;
      Zbase[bt * DZ + tid] = znew;
    }
    __syncthreads();
  }

  if (tid < 128) out[(size_t)b * DZ + tid] = zcurL[tid];
}

// ---- pass 1: gi[bt][c] = b_ih[c] + x[bt] @ W_ih  (input-only, fully parallel, fp32)
__global__ __launch_bounds__(384) void gi_precompute(
    const float* __restrict__ Y, const float* __restrict__ Mm,
    const float* __restrict__ Hh, const float* __restrict__ Wih,
    const float* __restrict__ bih, float* __restrict__ gi)
{
  __shared__ float Xs[XDIM][16];
  const int tid = threadIdx.x;
  const size_t bt0 = (size_t)blockIdx.x * 16;
  for (int idx = tid; idx < XDIM * 16; idx += 384) {
    int r = idx & 15, c = idx >> 4;
    size_t bt = bt0 + r;
    float v;
    if (c < 20)      v = Y[bt * NDYN + c];
    else if (c < 40) v = Mm[bt * NDYN + (c - 20)];
    else             v = Hh[bt * DH + (c - 40)];
    Xs[c][r] = v;
  }
  __syncthreads();
  float acc[16];
  const float bv = bih[tid];
  #pragma unroll
  for (int r = 0; r < 16; ++r) acc[r] = bv;
  for (int i = 0; i < XDIM; ++i) {
    float w = Wih[i * GCOLS + tid];
    const float4* xp = (const float4*)(&Xs[i][0]);
    #pragma unroll
    for (int q = 0; q < 4; ++q) {
      float4 xv = xp[q];
      acc[4*q + 0] += xv.x * w;
      acc[4*q + 1] += xv.y * w;
      acc[4*q + 2] += xv.z * w;
      acc[4*q + 3] += xv.w * w;
    }
  }
  #pragma unroll
  for (int r = 0; r < 16; ++r) gi[(bt0 + r) * GCOLS + tid] = acc[r];
}

extern "C" void kernel_launch(void* const* d_in, const int* in_sizes, int n_in,
                              void* d_out, int out_size, void* d_ws, size_t ws_size,
                              hipStream_t stream) {
  const float* z0   = (const float*)d_in[0];
  const float* tdyn = (const float*)d_in[1];
  const float* Y    = (const float*)d_in[2];
  const float* Mm   = (const float*)d_in[3];
  const float* Hh   = (const float*)d_in[4];
  const int*   lens = (const int*)d_in[5];
  const float* W0   = (const float*)d_in[6];
  const float* b0   = (const float*)d_in[7];
  const float* W1   = (const float*)d_in[8];
  const float* b1   = (const float*)d_in[9];
  const float* W2   = (const float*)d_in[10];
  const float* b2   = (const float*)d_in[11];
  const float* Wih  = (const float*)d_in[12];
  const float* bih  = (const float*)d_in[13];
  const float* Whh  = (const float*)d_in[14];
  const float* bhh  = (const float*)d_in[15];
  float* out = (float*)d_out;

  const size_t gi_bytes = (size_t)B_ * T_ * GCOLS * sizeof(float);
  const int use_gi = (ws_size >= gi_bytes) ? 1 : 0;
  float* gi = (float*)d_ws;

  if (use_gi)
    gi_precompute<<<(B_ * T_) / 16, 384, 0, stream>>>(Y, Mm, Hh, Wih, bih, gi);

  odernn_kernel<<<B_, 384, 0, stream>>>(
      z0, tdyn, Y, Mm, Hh, lens, W0, b0, W1, b1, W2, b2,
      Wih, bih, Whh, bhh, use_gi ? gi : nullptr, out, use_gi);
}

// Round 3
// 5246.804 us; speedup vs baseline: 8.8934x; 8.8934x over previous
//
#include <hip/hip_runtime.h>
#include <cstdint>
#include <cstddef>

#define B_    256
#define T_    1024
#define NDYN  20
#define DH    64
#define DZ    128
#define HIDN  64
#define GCOLS 384   // 3*DZ
#define XDIM  104   // 2*NDYN + DH

// Whh split: rows 0..99 in LDS (float4-interleaved), rows 100..127 in registers.
#define WHH_LDS_G 25          // 25 groups of 4 rows = rows 0..99
#define WHH_REG   28          // rows 100..127

// chunk-padded LDS index: 16-float chunks at stride 20 (conflict-free float4 reads)
__device__ __forceinline__ int cpad(int k) { return (k >> 4) * 20 + (k & 15); }

// DPP cross-lane add (VALU pipe, not LDS). CTRL: 0xB1=quad_perm(1,0,3,2) ~ xor1,
// 0x4E=quad_perm(2,3,0,1) ~ xor2, 0x141=row_half_mirror ~ xor4 (valid once quads uniform).
template<int CTRL, int XORMASK>
__device__ __forceinline__ float dpp_sum(float v) {
#if __has_builtin(__builtin_amdgcn_mov_dpp)
  int o = __builtin_amdgcn_mov_dpp(__float_as_int(v), CTRL, 0xF, 0xF, true);
  return v + __int_as_float(o);
#else
  return v + __shfl_xor(v, XORMASK);
#endif
}

__device__ __forceinline__ float tanh_fast(float x) {
  float a = __expf(-2.f * fabsf(x));
  return copysignf((1.f - a) / (1.f + a), x);
}
__device__ __forceinline__ float sigm(float x) { return 1.f / (1.f + __expf(-x)); }

// Register-budget history (3 rounds of evidence): the backend pins this kernel
// at 128 arch VGPRs regardless of launch_bounds / waves_per_eu / "a"-constraint
// asm (the asm round allocated the AGPR virtuals to SCRATCH: 76 GB of stores).
// Design consequence: per-thread persistent state must fit ~92 floats so peak
// (with staging) stays under 128. Whh[128 rows] therefore lives mostly in LDS
// (rows 0..99, 153.6 KB of the 160 KB/CU — we run 1 block/CU anyway) and only
// rows 100..127 (28 floats) + wA(32) + wB(32) stay register-resident.
__global__ __launch_bounds__(384, 1) void odernn_kernel(
    const float* __restrict__ z0, const float* __restrict__ tdyn,
    const float* __restrict__ Y, const float* __restrict__ Mm,
    const float* __restrict__ Hh, const int* __restrict__ lens,
    const float* __restrict__ W0, const float* __restrict__ b0,
    const float* __restrict__ W1, const float* __restrict__ b1,
    const float* __restrict__ W2, const float* __restrict__ b2,
    const float* __restrict__ Wih, const float* __restrict__ bih,
    const float* __restrict__ Whh, const float* __restrict__ bhh,
    const float* __restrict__ gi_pre, float* __restrict__ out, int use_gi)
{
  const int tid = threadIdx.x;
  const int b   = blockIdx.x;

  __shared__ __align__(16) float vinP[160];   // RK4 input v, 8 chunks of 16 @ stride 20
  __shared__ __align__(16) float h1P[80];     // 4 chunks
  __shared__ __align__(16) float h2P[80];     // 4 chunks
  __shared__ __align__(16) float zodeL[128];  // flat, float4-broadcast in GRU
  __shared__ float zcurL[128];
  __shared__ float gateL[384];
  __shared__ float gateN[128];
  __shared__ float xsL[112];
  // Whh rows 0..99, float4-interleaved: WhhP4[g*384+c] = {Whh[4g..4g+3][c]}.
  // GRU read: lane stride 16 B -> lanes tile all 32 banks evenly (BW-optimal).
  __shared__ __align__(16) float4 WhhP4[WHH_LDS_G * 384];   // 153.6 KB

  // Register-resident weights:
  //   whh28[28]: Whh rows 100..127, column tid
  //   wA[32]: tid<256 -> L0 slice ; tid>=256 -> L2 slice
  //   wB[32]: tid<128 -> L1 slice ; 128<=tid<256 -> L2 slice
  float wA[32], wB[32], whh28[WHH_REG];

  // ---- one-time staging of Whh rows 0..99 into LDS (coalesced, column tid) ----
  #pragma unroll 1
  for (int g = 0; g < WHH_LDS_G; ++g) {
    float4 w;
    w.x = Whh[(4 * g + 0) * GCOLS + tid];
    w.y = Whh[(4 * g + 1) * GCOLS + tid];
    w.z = Whh[(4 * g + 2) * GCOLS + tid];
    w.w = Whh[(4 * g + 3) * GCOLS + tid];
    WhhP4[g * 384 + tid] = w;
  }
  #pragma unroll
  for (int i = 0; i < WHH_REG; ++i)
    whh28[i] = Whh[(4 * WHH_LDS_G + i) * GCOLS + tid];

  if (tid < 256) {            // L0: jg=tid>>3 (2 outputs), p=tid&7 (K-chunk of 16)
    const int jg = tid >> 3, p = tid & 7, j0 = 2 * jg, kb = 16 * p;
    #pragma unroll
    for (int i = 0; i < 16; ++i) {
      wA[i]      = W0[(kb + i) * HIDN + j0];
      wA[16 + i] = W0[(kb + i) * HIDN + j0 + 1];
    }
  } else {                    // L2 (upper half of thread slots)
    const int u = tid - 128, jg = u >> 2, p = u & 3, j0 = 2 * jg, kb = 16 * p;
    #pragma unroll
    for (int i = 0; i < 16; ++i) {
      wA[i]      = W2[(kb + i) * DZ + j0];
      wA[16 + i] = W2[(kb + i) * DZ + j0 + 1];
    }
  }
  if (tid < 128) {            // L1: jg=tid>>2, p=tid&3
    const int jg = tid >> 2, p = tid & 3, j0 = 2 * jg, kb = 16 * p;
    #pragma unroll
    for (int i = 0; i < 16; ++i) {
      wB[i]      = W1[(kb + i) * HIDN + j0];
      wB[16 + i] = W1[(kb + i) * HIDN + j0 + 1];
    }
  } else if (tid < 256) {     // L2 (lower half of thread slots)
    const int u = tid - 128, jg = u >> 2, p = u & 3, j0 = 2 * jg, kb = 16 * p;
    #pragma unroll
    for (int i = 0; i < 16; ++i) {
      wB[i]      = W2[(kb + i) * DZ + j0];
      wB[16 + i] = W2[(kb + i) * DZ + j0 + 1];
    }
  }

  float b0r = 0.f, b1r = 0.f, b2r = 0.f;
  if (tid < 256 && (tid & 7) < 2) b0r = b0[2 * (tid >> 3) + (tid & 7)];
  if (tid < 128 && (tid & 3) < 2) b1r = b1[2 * (tid >> 2) + (tid & 3)];
  if (tid >= 128 && ((tid - 128) & 3) < 2)
    b2r = b2[2 * ((tid - 128) >> 2) + ((tid - 128) & 3)];
  const float bhhr = bhh[tid];
  const float bihr = bih[tid];
  const int   lenb = lens[b];

  if (tid < 128) {
    float zv = z0[(size_t)b * DZ + tid];
    vinP[cpad(tid)] = zv;
    zcurL[tid] = zv;
  }
  __syncthreads();

  float* Zbase = out + (size_t)B_ * DZ;
  const float* tdb = tdyn + (size_t)b * T_;

  const int u2 = tid - 128, jg2 = u2 >> 2, p2 = u2 & 3;  // L2 role (valid tid>=128)
  const int j2 = 2 * jg2 + p2;                           // L2 writer output (p2<2)

  #pragma unroll 1
  for (int t = 0; t < T_; ++t) {
    const size_t bt = (size_t)b * T_ + t;
    // dt computed per-thread from global tdyn (no serializing LDS scalar):
    // t==0 -> dt = 0 exactly (matches reference's t_prev init = t_dyn[:,0]).
    const float dt = (t == 0) ? 0.f : fmaxf(tdb[t] - tdb[t - 1], 0.f);

    float gival = 0.f;
    if (use_gi) {
      gival = gi_pre[bt * GCOLS + tid];   // prefetch; consumed ~500 cyc later
    } else if (tid < XDIM) {
      float v;
      if (tid < 20)      v = Y[bt * NDYN + tid];
      else if (tid < 40) v = Mm[bt * NDYN + (tid - 20)];
      else               v = Hh[bt * DH + (tid - 40)];
      xsL[tid] = v;
    }

    float zreg = 0.f, kacc = 0.f;
    if (tid >= 128 && p2 < 2) zreg = zcurL[j2];

    // rolled: 4 RK stages are barrier-serialized anyway; rolling shrinks live
    // ranges / scheduling windows -> keeps peak arch VGPRs under the 128 cap.
    #pragma unroll 1
    for (int e = 0; e < 4; ++e) {
      // ---- L0: 64 outs, K=128 ---- (threads 0..255, group of 8, 2 outs each)
      if (tid < 256) {
        const int p = tid & 7, jg = tid >> 3;
        const float4* vp = (const float4*)&vinP[p * 20];
        float a0 = 0.f, a1 = 0.f;
        #pragma unroll
        for (int q = 0; q < 4; ++q) {
          float4 v = vp[q];
          a0 += wA[4*q+0]*v.x + wA[4*q+1]*v.y + wA[4*q+2]*v.z + wA[4*q+3]*v.w;
          a1 += wA[16+4*q+0]*v.x + wA[16+4*q+1]*v.y + wA[16+4*q+2]*v.z + wA[16+4*q+3]*v.w;
        }
        a0 = dpp_sum<0xB1,1>(a0); a0 = dpp_sum<0x4E,2>(a0); a0 = dpp_sum<0x141,4>(a0);
        a1 = dpp_sum<0xB1,1>(a1); a1 = dpp_sum<0x4E,2>(a1); a1 = dpp_sum<0x141,4>(a1);
        if (p < 2)
          h1P[cpad(2 * jg + p)] = tanh_fast((p ? a1 : a0) + b0r);
      }
      __syncthreads();
      // ---- L1: 64 outs, K=64 ---- (threads 0..127, group of 4)
      if (tid < 128) {
        const int p = tid & 3, jg = tid >> 2;
        const float4* hp = (const float4*)&h1P[p * 20];
        float a0 = 0.f, a1 = 0.f;
        #pragma unroll
        for (int q = 0; q < 4; ++q) {
          float4 v = hp[q];
          a0 += wB[4*q+0]*v.x + wB[4*q+1]*v.y + wB[4*q+2]*v.z + wB[4*q+3]*v.w;
          a1 += wB[16+4*q+0]*v.x + wB[16+4*q+1]*v.y + wB[16+4*q+2]*v.z + wB[16+4*q+3]*v.w;
        }
        a0 = dpp_sum<0xB1,1>(a0); a0 = dpp_sum<0x4E,2>(a0);
        a1 = dpp_sum<0xB1,1>(a1); a1 = dpp_sum<0x4E,2>(a1);
        if (p < 2)
          h2P[cpad(2 * jg + p)] = tanh_fast((p ? a1 : a0) + b1r);
      }
      __syncthreads();
      // ---- L2: 128 outs, K=64 ---- (threads 128..383, group of 4)
      if (tid >= 128) {
        const float4* hp = (const float4*)&h2P[p2 * 20];
        float a0 = 0.f, a1 = 0.f;
        if (tid < 256) {
          #pragma unroll
          for (int q = 0; q < 4; ++q) {
            float4 v = hp[q];
            a0 += wB[4*q+0]*v.x + wB[4*q+1]*v.y + wB[4*q+2]*v.z + wB[4*q+3]*v.w;
            a1 += wB[16+4*q+0]*v.x + wB[16+4*q+1]*v.y + wB[16+4*q+2]*v.z + wB[16+4*q+3]*v.w;
          }
        } else {
          #pragma unroll
          for (int q = 0; q < 4; ++q) {
            float4 v = hp[q];
            a0 += wA[4*q+0]*v.x + wA[4*q+1]*v.y + wA[4*q+2]*v.z + wA[4*q+3]*v.w;
            a1 += wA[16+4*q+0]*v.x + wA[16+4*q+1]*v.y + wA[16+4*q+2]*v.z + wA[16+4*q+3]*v.w;
          }
        }
        a0 = dpp_sum<0xB1,1>(a0); a0 = dpp_sum<0x4E,2>(a0);
        a1 = dpp_sum<0xB1,1>(a1); a1 = dpp_sum<0x4E,2>(a1);
        if (p2 < 2) {
          const float kv = dt * ((p2 ? a1 : a0) + b2r);
          if (e == 0)      kacc = kv;
          else if (e == 3) kacc += kv;
          else             kacc += 2.f * kv;
          if (e < 3) {
            const float a = (e == 2) ? 1.f : 0.5f;
            vinP[cpad(j2)] = zreg + a * kv;
          } else {
            zodeL[j2] = zreg + kacc * (1.f / 6.f);
          }
        }
      }
      __syncthreads();
    }

    // ---- GRU: column tid. Whh rows 0..99 from LDS (float4-interleaved,
    // 2-deep manual pipeline), rows 100..127 from registers. ----
    {
      float gh0 = bhhr, gh1 = 0.f;
      const float4* zq = (const float4*)zodeL;
      #pragma unroll 1
      for (int g = 0; g < WHH_LDS_G - 1; g += 2) {
        float4 w0 = WhhP4[g * 384 + tid];
        float4 w1 = WhhP4[(g + 1) * 384 + tid];
        float4 za = zq[g];
        float4 zb = zq[g + 1];
        gh0 += w0.x*za.x + w0.y*za.y + w0.z*za.z + w0.w*za.w;
        gh1 += w1.x*zb.x + w1.y*zb.y + w1.z*zb.z + w1.w*zb.w;
      }
      {  // tail group g = 24
        float4 w0 = WhhP4[(WHH_LDS_G - 1) * 384 + tid];
        float4 za = zq[WHH_LDS_G - 1];
        gh0 += w0.x*za.x + w0.y*za.y + w0.z*za.z + w0.w*za.w;
      }
      #pragma unroll   // MUST be fully unrolled: whh28 indices compile-time (rule #20)
      for (int q = 0; q < 7; ++q) {
        float4 z = zq[WHH_LDS_G + q];
        gh1 += whh28[4*q+0]*z.x + whh28[4*q+1]*z.y + whh28[4*q+2]*z.z + whh28[4*q+3]*z.w;
      }
      float gh = gh0 + gh1;
      float gi;
      if (use_gi) gi = gival;
      else {
        gi = bihr;
        for (int i = 0; i < XDIM; ++i) gi += xsL[i] * Wih[(size_t)i * GCOLS + tid];
      }
      if (tid < 256) gateL[tid] = gi + gh;
      else { gateL[tid] = gh; gateN[tid - 256] = gi; }
    }
    __syncthreads();

    if (tid < 128) {
      const float r  = sigm(gateL[tid]);
      const float uu = sigm(gateL[128 + tid]);
      const float n  = tanh_fast(gateN[tid] + r * gateL[256 + tid]);
      const float zo = zodeL[tid];
      const float zn = (1.f - uu) * n + uu * zo;
      const float znew = (t < lenb) ? zn : zo;
      vinP[cpad(tid)] = znew;
      zcurL[tid] = znew;
      Zbase[bt * DZ + tid] = znew;
    }
    __syncthreads();
  }

  if (tid < 128) out[(size_t)b * DZ + tid] = zcurL[tid];
}

// ---- pass 1: gi[bt][c] = b_ih[c] + x[bt] @ W_ih  (input-only, fully parallel, fp32)
__global__ __launch_bounds__(384) void gi_precompute(
    const float* __restrict__ Y, const float* __restrict__ Mm,
    const float* __restrict__ Hh, const float* __restrict__ Wih,
    const float* __restrict__ bih, float* __restrict__ gi)
{
  __shared__ float Xs[XDIM][16];
  const int tid = threadIdx.x;
  const size_t bt0 = (size_t)blockIdx.x * 16;
  for (int idx = tid; idx < XDIM * 16; idx += 384) {
    int r = idx & 15, c = idx >> 4;
    size_t bt = bt0 + r;
    float v;
    if (c < 20)      v = Y[bt * NDYN + c];
    else if (c < 40) v = Mm[bt * NDYN + (c - 20)];
    else             v = Hh[bt * DH + (c - 40)];
    Xs[c][r] = v;
  }
  __syncthreads();
  float acc[16];
  const float bv = bih[tid];
  #pragma unroll
  for (int r = 0; r < 16; ++r) acc[r] = bv;
  for (int i = 0; i < XDIM; ++i) {
    float w = Wih[i * GCOLS + tid];
    const float4* xp = (const float4*)(&Xs[i][0]);
    #pragma unroll
    for (int q = 0; q < 4; ++q) {
      float4 xv = xp[q];
      acc[4*q + 0] += xv.x * w;
      acc[4*q + 1] += xv.y * w;
      acc[4*q + 2] += xv.z * w;
      acc[4*q + 3] += xv.w * w;
    }
  }
  #pragma unroll
  for (int r = 0; r < 16; ++r) gi[(bt0 + r) * GCOLS + tid] = acc[r];
}

extern "C" void kernel_launch(void* const* d_in, const int* in_sizes, int n_in,
                              void* d_out, int out_size, void* d_ws, size_t ws_size,
                              hipStream_t stream) {
  const float* z0   = (const float*)d_in[0];
  const float* tdyn = (const float*)d_in[1];
  const float* Y    = (const float*)d_in[2];
  const float* Mm   = (const float*)d_in[3];
  const float* Hh   = (const float*)d_in[4];
  const int*   lens = (const int*)d_in[5];
  const float* W0   = (const float*)d_in[6];
  const float* b0   = (const float*)d_in[7];
  const float* W1   = (const float*)d_in[8];
  const float* b1   = (const float*)d_in[9];
  const float* W2   = (const float*)d_in[10];
  const float* b2   = (const float*)d_in[11];
  const float* Wih  = (const float*)d_in[12];
  const float* bih  = (const float*)d_in[13];
  const float* Whh  = (const float*)d_in[14];
  const float* bhh  = (const float*)d_in[15];
  float* out = (float*)d_out;

  const size_t gi_bytes = (size_t)B_ * T_ * GCOLS * sizeof(float);
  const int use_gi = (ws_size >= gi_bytes) ? 1 : 0;
  float* gi = (float*)d_ws;

  if (use_gi)
    gi_precompute<<<(B_ * T_) / 16, 384, 0, stream>>>(Y, Mm, Hh, Wih, bih, gi);

  odernn_kernel<<<B_, 384, 0, stream>>>(
      z0, tdyn, Y, Mm, Hh, lens, W0, b0, W1, b1, W2, b2,
      Wih, bih, Whh, bhh, use_gi ? gi : nullptr, out, use_gi);
}

// Round 4
// 5028.527 us; speedup vs baseline: 9.2794x; 1.0434x over previous
//
#include <hip/hip_runtime.h>
#include <cstdint>
#include <cstddef>

#define B_    256
#define T_    1024
#define NDYN  20
#define DH    64
#define DZ    128
#define HIDN  64
#define GCOLS 384   // 3*DZ
#define XDIM  104   // 2*NDYN + DH
#define THR   512   // 8 waves: every RK4 phase uses all lanes

// Whh split: rows 0..99 in LDS (float4-interleaved), rows 100..127 in registers.
#define WHH_LDS_G 25          // 25 groups of 4 rows = rows 0..99
#define WHH_REG   28          // rows 100..127

// chunk-padded LDS index: 16-float chunks at stride 20 (conflict-free float4 reads)
__device__ __forceinline__ int cpad(int k) { return (k >> 4) * 20 + (k & 15); }

// Raw block barrier: LDS ordering only (lgkmcnt), NO vmcnt drain.
// __syncthreads() emits s_waitcnt vmcnt(0) before s_barrier, which pulls the
// gi_pre global load (~400-900 cy) and Z-store acks into the 14-phase serial
// chain every step. With lgkm-only, the gi load issued at step start has ~13
// barriers to land; the compiler still emits its own vmcnt wait at the USE.
#define BAR() do { asm volatile("s_waitcnt lgkmcnt(0)" ::: "memory"); \
                   __builtin_amdgcn_s_barrier(); } while (0)

// DPP cross-lane add (VALU pipe, not LDS). CTRL: 0xB1=quad_perm(1,0,3,2) ~ xor1,
// 0x4E=quad_perm(2,3,0,1) ~ xor2, 0x141=row_half_mirror ~ xor4 (valid once quads uniform).
template<int CTRL, int XORMASK>
__device__ __forceinline__ float dpp_sum(float v) {
#if __has_builtin(__builtin_amdgcn_mov_dpp)
  int o = __builtin_amdgcn_mov_dpp(__float_as_int(v), CTRL, 0xF, 0xF, true);
  return v + __int_as_float(o);
#else
  return v + __shfl_xor(v, XORMASK);
#endif
}

__device__ __forceinline__ float tanh_fast(float x) {
  float a = __expf(-2.f * fabsf(x));
  return copysignf((1.f - a) / (1.f + a), x);
}
__device__ __forceinline__ float sigm(float x) { return 1.f / (1.f + __expf(-x)); }

// Register-budget history: backend pins this kernel at 128 arch VGPRs regardless
// of launch_bounds / waves_per_eu / AGPR asm (R1/R2 evidence; AGPR attempt went
// to scratch: 76 GB stores). Persistent per-thread state must stay ~<100 floats.
// This 512-thread partition: w0r(16)+w1r(8)+w2r(16)+whh28(28) = 68 persistent.
// Whh rows 0..99 live in LDS (153.6 KB; 1 block/CU anyway).
__global__ __launch_bounds__(THR, 1) void odernn_kernel(
    const float* __restrict__ z0, const float* __restrict__ tdyn,
    const float* __restrict__ Y, const float* __restrict__ Mm,
    const float* __restrict__ Hh, const int* __restrict__ lens,
    const float* __restrict__ W0, const float* __restrict__ b0,
    const float* __restrict__ W1, const float* __restrict__ b1,
    const float* __restrict__ W2, const float* __restrict__ b2,
    const float* __restrict__ Wih, const float* __restrict__ bih,
    const float* __restrict__ Whh, const float* __restrict__ bhh,
    const float* __restrict__ gi_pre, float* __restrict__ out, int use_gi)
{
  const int tid = threadIdx.x;
  const int b   = blockIdx.x;

  __shared__ __align__(16) float vinP[160];   // RK4 input v, 8 chunks of 16 @ stride 20
  __shared__ __align__(16) float h1P[80];     // 4 chunks
  __shared__ __align__(16) float h2P[80];     // 4 chunks
  __shared__ __align__(16) float zodeL[128];  // flat, float4-broadcast in GRU
  __shared__ float zcurL[128];
  __shared__ float gateL[384];
  __shared__ float gateN[128];
  __shared__ float xsL[112];
  // Whh rows 0..99, float4-interleaved: WhhP4[g*384+c] = {Whh[4g..4g+3][c]}.
  // GRU read: lane stride 16 B -> lanes tile all 32 banks evenly (BW-optimal).
  __shared__ __align__(16) float4 WhhP4[WHH_LDS_G * 384];   // 153.6 KB

  // Roles (every thread has all three MLP roles -> full lanes every phase):
  //   L0: out jg0 = tid>>3 (0..63),  K-chunk 16*p0, p0 = tid&7  -> w0r[16]
  //   L1: out jg0,                   K-chunk  8*p0              -> w1r[8]
  //   L2: out j2  = tid>>2 (0..127), K-chunk 16*p2, p2 = tid&3  -> w2r[16]
  const int jg0 = tid >> 3, p0 = tid & 7;
  const int j2  = tid >> 2, p2 = tid & 3;
  const int gcol = (tid < GCOLS) ? tid : 0;   // GRU column (guard OOB for tid>=384)

  float w0r[16], w1r[8], w2r[16], whh28[WHH_REG];

  // ---- one-time staging of Whh rows 0..99 into LDS (coalesced, column tid) ----
  if (tid < GCOLS) {
    #pragma unroll 1
    for (int g = 0; g < WHH_LDS_G; ++g) {
      float4 w;
      w.x = Whh[(4 * g + 0) * GCOLS + tid];
      w.y = Whh[(4 * g + 1) * GCOLS + tid];
      w.z = Whh[(4 * g + 2) * GCOLS + tid];
      w.w = Whh[(4 * g + 3) * GCOLS + tid];
      WhhP4[g * 384 + tid] = w;
    }
  }
  #pragma unroll
  for (int i = 0; i < WHH_REG; ++i)
    whh28[i] = Whh[(4 * WHH_LDS_G + i) * GCOLS + gcol];

  #pragma unroll
  for (int i = 0; i < 16; ++i) w0r[i] = W0[(16 * p0 + i) * HIDN + jg0];
  #pragma unroll
  for (int i = 0; i < 8; ++i)  w1r[i] = W1[(8 * p0 + i) * HIDN + jg0];
  #pragma unroll
  for (int i = 0; i < 16; ++i) w2r[i] = W2[(16 * p2 + i) * DZ + j2];

  float b0r = 0.f, b1r = 0.f, b2r = 0.f;
  if (p0 == 0) { b0r = b0[jg0]; b1r = b1[jg0]; }
  if (p2 == 0) b2r = b2[j2];
  const float bhhr = bhh[gcol];
  const float bihr = bih[gcol];
  const int   lenb = lens[b];

  if (tid < 128) {
    float zv = z0[(size_t)b * DZ + tid];
    vinP[cpad(tid)] = zv;
    zcurL[tid] = zv;
  }
  __syncthreads();   // full barrier once, before the loop

  float* Zbase = out + (size_t)B_ * DZ;
  const float* tdb = tdyn + (size_t)b * T_;

  #pragma unroll 1
  for (int t = 0; t < T_; ++t) {
    const size_t bt = (size_t)b * T_ + t;
    // dt computed per-thread from global tdyn (L1-resident line).
    // t==0 -> dt = 0 exactly (matches reference's t_prev init = t_dyn[:,0]).
    const float dt = (t == 0) ? 0.f : fmaxf(tdb[t] - tdb[t - 1], 0.f);

    float gival = 0.f;
    if (use_gi) {
      if (tid < GCOLS) gival = gi_pre[bt * GCOLS + tid];  // lands ~13 barriers later
    } else if (tid < XDIM) {
      float v;
      if (tid < 20)      v = Y[bt * NDYN + tid];
      else if (tid < 40) v = Mm[bt * NDYN + (tid - 20)];
      else               v = Hh[bt * DH + (tid - 40)];
      xsL[tid] = v;
    }

    float zreg = 0.f, kacc = 0.f;
    if (p2 == 0) zreg = zcurL[j2];

    // rolled: 4 RK stages are barrier-serialized anyway; rolling shrinks live
    // ranges / scheduling windows -> keeps peak arch VGPRs under the 128 cap.
    #pragma unroll 1
    for (int e = 0; e < 4; ++e) {
      // ---- L0: 64 outs, K=128; 8 threads/out, K-chunk 16 (all 512 lanes) ----
      // read &vinP[p0*20]: word banks tile 0..31 exactly once -> conflict-free
      {
        const float4* vp = (const float4*)&vinP[p0 * 20];
        float a0 = 0.f;
        #pragma unroll
        for (int q = 0; q < 4; ++q) {
          float4 v = vp[q];
          a0 += w0r[4*q+0]*v.x + w0r[4*q+1]*v.y + w0r[4*q+2]*v.z + w0r[4*q+3]*v.w;
        }
        a0 = dpp_sum<0xB1,1>(a0); a0 = dpp_sum<0x4E,2>(a0); a0 = dpp_sum<0x141,4>(a0);
        if (p0 == 0)
          h1P[cpad(jg0)] = tanh_fast(a0 + b0r);
      }
      BAR();
      // ---- L1: 64 outs, K=64; 8 threads/out, K-chunk 8 (all 512 lanes) ----
      // h1[8p0..8p0+7] is contiguous in the padded layout (8p0 mod 16 in {0,8})
      {
        const float4* hp = (const float4*)&h1P[cpad(8 * p0)];
        float4 v0 = hp[0], v1 = hp[1];
        float a0 = w1r[0]*v0.x + w1r[1]*v0.y + w1r[2]*v0.z + w1r[3]*v0.w
                 + w1r[4]*v1.x + w1r[5]*v1.y + w1r[6]*v1.z + w1r[7]*v1.w;
        a0 = dpp_sum<0xB1,1>(a0); a0 = dpp_sum<0x4E,2>(a0); a0 = dpp_sum<0x141,4>(a0);
        if (p0 == 0)
          h2P[cpad(jg0)] = tanh_fast(a0 + b1r);
      }
      BAR();
      // ---- L2: 128 outs, K=64; 4 threads/out, K-chunk 16 (all 512 lanes) ----
      {
        const float4* hp = (const float4*)&h2P[p2 * 20];
        float a0 = 0.f;
        #pragma unroll
        for (int q = 0; q < 4; ++q) {
          float4 v = hp[q];
          a0 += w2r[4*q+0]*v.x + w2r[4*q+1]*v.y + w2r[4*q+2]*v.z + w2r[4*q+3]*v.w;
        }
        a0 = dpp_sum<0xB1,1>(a0); a0 = dpp_sum<0x4E,2>(a0);
        if (p2 == 0) {
          const float kv = dt * (a0 + b2r);
          if (e == 0)      kacc = kv;
          else if (e == 3) kacc += kv;
          else             kacc += 2.f * kv;
          if (e < 3) {
            const float a = (e == 2) ? 1.f : 0.5f;
            vinP[cpad(j2)] = zreg + a * kv;
          } else {
            zodeL[j2] = zreg + kacc * (1.f / 6.f);
          }
        }
      }
      BAR();
    }

    // ---- GRU matvec: column gcol (tid<384). Whh rows 0..99 from LDS
    // (float4-interleaved, 2-deep pipeline), rows 100..127 from registers. ----
    if (tid < GCOLS) {
      float gh0 = bhhr, gh1 = 0.f;
      const float4* zq = (const float4*)zodeL;
      #pragma unroll 1
      for (int g = 0; g < WHH_LDS_G - 1; g += 2) {
        float4 w0 = WhhP4[g * 384 + tid];
        float4 w1 = WhhP4[(g + 1) * 384 + tid];
        float4 za = zq[g];
        float4 zb = zq[g + 1];
        gh0 += w0.x*za.x + w0.y*za.y + w0.z*za.z + w0.w*za.w;
        gh1 += w1.x*zb.x + w1.y*zb.y + w1.z*zb.z + w1.w*zb.w;
      }
      {  // tail group g = 24
        float4 w0 = WhhP4[(WHH_LDS_G - 1) * 384 + tid];
        float4 za = zq[WHH_LDS_G - 1];
        gh0 += w0.x*za.x + w0.y*za.y + w0.z*za.z + w0.w*za.w;
      }
      #pragma unroll   // MUST be fully unrolled: whh28 indices compile-time
      for (int q = 0; q < 7; ++q) {
        float4 z = zq[WHH_LDS_G + q];
        gh1 += whh28[4*q+0]*z.x + whh28[4*q+1]*z.y + whh28[4*q+2]*z.z + whh28[4*q+3]*z.w;
      }
      float gh = gh0 + gh1;
      float gi;
      if (use_gi) gi = gival;
      else {
        gi = bihr;
        for (int i = 0; i < XDIM; ++i) gi += xsL[i] * Wih[(size_t)i * GCOLS + tid];
      }
      if (tid < 256) gateL[tid] = gi + gh;
      else { gateL[tid] = gh; gateN[tid - 256] = gi; }
    }
    BAR();

    if (tid < 128) {
      const float r  = sigm(gateL[tid]);
      const float uu = sigm(gateL[128 + tid]);
      const float n  = tanh_fast(gateN[tid] + r * gateL[256 + tid]);
      const float zo = zodeL[tid];
      const float zn = (1.f - uu) * n + uu * zo;
      const float znew = (t < lenb) ? zn : zo;
      vinP[cpad(tid)] = znew;
      zcurL[tid] = znew;
      Zbase[bt * DZ + tid] = znew;
    }
    BAR();
  }

  __syncthreads();
  if (tid < 128) out[(size_t)b * DZ + tid] = zcurL[tid];
}

// ---- pass 1: gi[bt][c] = b_ih[c] + x[bt] @ W_ih  (input-only, fully parallel, fp32)
__global__ __launch_bounds__(384) void gi_precompute(
    const float* __restrict__ Y, const float* __restrict__ Mm,
    const float* __restrict__ Hh, const float* __restrict__ Wih,
    const float* __restrict__ bih, float* __restrict__ gi)
{
  __shared__ float Xs[XDIM][16];
  const int tid = threadIdx.x;
  const size_t bt0 = (size_t)blockIdx.x * 16;
  for (int idx = tid; idx < XDIM * 16; idx += 384) {
    int r = idx & 15, c = idx >> 4;
    size_t bt = bt0 + r;
    float v;
    if (c < 20)      v = Y[bt * NDYN + c];
    else if (c < 40) v = Mm[bt * NDYN + (c - 20)];
    else             v = Hh[bt * DH + (c - 40)];
    Xs[c][r] = v;
  }
  __syncthreads();
  float acc[16];
  const float bv = bih[tid];
  #pragma unroll
  for (int r = 0; r < 16; ++r) acc[r] = bv;
  for (int i = 0; i < XDIM; ++i) {
    float w = Wih[i * GCOLS + tid];
    const float4* xp = (const float4*)(&Xs[i][0]);
    #pragma unroll
    for (int q = 0; q < 4; ++q) {
      float4 xv = xp[q];
      acc[4*q + 0] += xv.x * w;
      acc[4*q + 1] += xv.y * w;
      acc[4*q + 2] += xv.z * w;
      acc[4*q + 3] += xv.w * w;
    }
  }
  #pragma unroll
  for (int r = 0; r < 16; ++r) gi[(bt0 + r) * GCOLS + tid] = acc[r];
}

extern "C" void kernel_launch(void* const* d_in, const int* in_sizes, int n_in,
                              void* d_out, int out_size, void* d_ws, size_t ws_size,
                              hipStream_t stream) {
  const float* z0   = (const float*)d_in[0];
  const float* tdyn = (const float*)d_in[1];
  const float* Y    = (const float*)d_in[2];
  const float* Mm   = (const float*)d_in[3];
  const float* Hh   = (const float*)d_in[4];
  const int*   lens = (const int*)d_in[5];
  const float* W0   = (const float*)d_in[6];
  const float* b0   = (const float*)d_in[7];
  const float* W1   = (const float*)d_in[8];
  const float* b1   = (const float*)d_in[9];
  const float* W2   = (const float*)d_in[10];
  const float* b2   = (const float*)d_in[11];
  const float* Wih  = (const float*)d_in[12];
  const float* bih  = (const float*)d_in[13];
  const float* Whh  = (const float*)d_in[14];
  const float* bhh  = (const float*)d_in[15];
  float* out = (float*)d_out;

  const size_t gi_bytes = (size_t)B_ * T_ * GCOLS * sizeof(float);
  const int use_gi = (ws_size >= gi_bytes) ? 1 : 0;
  float* gi = (float*)d_ws;

  if (use_gi)
    gi_precompute<<<(B_ * T_) / 16, 384, 0, stream>>>(Y, Mm, Hh, Wih, bih, gi);

  odernn_kernel<<<B_, THR, 0, stream>>>(
      z0, tdyn, Y, Mm, Hh, lens, W0, b0, W1, b1, W2, b2,
      Wih, bih, Whh, bhh, use_gi ? gi : nullptr, out, use_gi);
}

// Round 5
// 4727.469 us; speedup vs baseline: 9.8704x; 1.0637x over previous
//
#include <hip/hip_runtime.h>
#include <cstdint>
#include <cstddef>

#define B_    256
#define T_    1024
#define NDYN  20
#define DH    64
#define DZ    128
#define HIDN  64
#define GCOLS 384   // 3*DZ
#define XDIM  104   // 2*NDYN + DH
#define THR   512   // 8 waves: every RK4 phase uses all lanes

// Whh split: rows 0..67 in LDS (float4-interleaved), rows 68..127 in registers
// as TWO arrays of <=32 floats (SROA promotes <=32-elem arrays reliably; the
// R0/R2 spills were promotion failures of a single 128-float array, not an
// allocator budget cap).
#define WHH_LDS_G 17          // 17 groups of 4 rows = rows 0..67
#define WHH_REGA  32          // rows 68..99
#define WHH_REGB  28          // rows 100..127

// chunk-padded LDS index: 16-float chunks at stride 20 (conflict-free float4 reads)
__device__ __forceinline__ int cpad(int k) { return (k >> 4) * 20 + (k & 15); }

// Raw block barrier: LDS ordering only (lgkmcnt), NO vmcnt drain.
// __syncthreads() emits s_waitcnt vmcnt(0) before s_barrier, which pulls the
// gi_pre global load (~400-900 cy) and Z-store acks into the 14-phase serial
// chain every step. With lgkm-only, the gi load issued at step start has ~13
// barriers to land; the compiler still emits its own vmcnt wait at the USE.
#define BAR() do { asm volatile("s_waitcnt lgkmcnt(0)" ::: "memory"); \
                   __builtin_amdgcn_s_barrier(); } while (0)

// DPP cross-lane add (VALU pipe, not LDS). CTRL: 0xB1=quad_perm(1,0,3,2) ~ xor1,
// 0x4E=quad_perm(2,3,0,1) ~ xor2, 0x141=row_half_mirror ~ xor4 (valid once quads uniform).
template<int CTRL, int XORMASK>
__device__ __forceinline__ float dpp_sum(float v) {
#if __has_builtin(__builtin_amdgcn_mov_dpp)
  int o = __builtin_amdgcn_mov_dpp(__float_as_int(v), CTRL, 0xF, 0xF, true);
  return v + __int_as_float(o);
#else
  return v + __shfl_xor(v, XORMASK);
#endif
}

__device__ __forceinline__ float tanh_fast(float x) {
  float a = __expf(-2.f * fabsf(x));
  return copysignf((1.f - a) / (1.f + a), x);
}
__device__ __forceinline__ float sigm(float x) { return 1.f / (1.f + __expf(-x)); }

// Persistent per-thread regs: w0r(16)+w1r(8)+w2r(16)+whhA(32)+whhB(28) = 100
// floats + ~15 scalars -> demands ~150 VGPRs. launch_bounds(512,1) allows up
// to 512; this round probes whether the allocator grants >128 (R0/R2 failures
// re-diagnosed as SROA array-promotion issues, avoided here via <=32 arrays).
__global__ __launch_bounds__(THR, 1) void odernn_kernel(
    const float* __restrict__ z0, const float* __restrict__ tdyn,
    const float* __restrict__ Y, const float* __restrict__ Mm,
    const float* __restrict__ Hh, const int* __restrict__ lens,
    const float* __restrict__ W0, const float* __restrict__ b0,
    const float* __restrict__ W1, const float* __restrict__ b1,
    const float* __restrict__ W2, const float* __restrict__ b2,
    const float* __restrict__ Wih, const float* __restrict__ bih,
    const float* __restrict__ Whh, const float* __restrict__ bhh,
    const float* __restrict__ gi_pre, float* __restrict__ out, int use_gi)
{
  const int tid = threadIdx.x;
  const int b   = blockIdx.x;

  __shared__ __align__(16) float vinP[160];   // RK4 input v, 8 chunks of 16 @ stride 20
  __shared__ __align__(16) float h1P[80];     // 4 chunks
  __shared__ __align__(16) float h2P[80];     // 4 chunks
  __shared__ __align__(16) float zodeL[128];  // flat, float4-broadcast in GRU
  __shared__ float zcurL[128];
  __shared__ float gateL[384];
  __shared__ float gateN[128];
  __shared__ float xsL[112];
  __shared__ float dtL[T_];                   // per-step dt, precomputed at init (4KB)
  // Whh rows 0..67, float4-interleaved: WhhP4[g*384+c] = {Whh[4g..4g+3][c]}.
  // GRU read: lane stride 16 B -> lanes tile all 32 banks evenly (BW-optimal).
  __shared__ __align__(16) float4 WhhP4[WHH_LDS_G * 384];   // 104.4 KB

  // Roles (every thread has all three MLP roles -> full lanes every phase):
  //   L0: out jg0 = tid>>3 (0..63),  K-chunk 16*p0, p0 = tid&7  -> w0r[16]
  //   L1: out jg0,                   K-chunk  8*p0              -> w1r[8]
  //   L2: out j2  = tid>>2 (0..127), K-chunk 16*p2, p2 = tid&3  -> w2r[16]
  const int jg0 = tid >> 3, p0 = tid & 7;
  const int j2  = tid >> 2, p2 = tid & 3;
  const int gcol = (tid < GCOLS) ? tid : 0;   // GRU column (guard OOB for tid>=384)

  float w0r[16], w1r[8], w2r[16], whhA[WHH_REGA], whhB[WHH_REGB];

  // ---- one-time staging of Whh rows 0..67 into LDS (coalesced, column tid) ----
  if (tid < GCOLS) {
    #pragma unroll 1
    for (int g = 0; g < WHH_LDS_G; ++g) {
      float4 w;
      w.x = Whh[(4 * g + 0) * GCOLS + tid];
      w.y = Whh[(4 * g + 1) * GCOLS + tid];
      w.z = Whh[(4 * g + 2) * GCOLS + tid];
      w.w = Whh[(4 * g + 3) * GCOLS + tid];
      WhhP4[g * 384 + tid] = w;
    }
  }
  #pragma unroll
  for (int i = 0; i < WHH_REGA; ++i)
    whhA[i] = Whh[(4 * WHH_LDS_G + i) * GCOLS + gcol];          // rows 68..99
  #pragma unroll
  for (int i = 0; i < WHH_REGB; ++i)
    whhB[i] = Whh[(4 * WHH_LDS_G + WHH_REGA + i) * GCOLS + gcol]; // rows 100..127

  #pragma unroll
  for (int i = 0; i < 16; ++i) w0r[i] = W0[(16 * p0 + i) * HIDN + jg0];
  #pragma unroll
  for (int i = 0; i < 8; ++i)  w1r[i] = W1[(8 * p0 + i) * HIDN + jg0];
  #pragma unroll
  for (int i = 0; i < 16; ++i) w2r[i] = W2[(16 * p2 + i) * DZ + j2];

  const float* tdb = tdyn + (size_t)b * T_;
  // dt table: dtL[t] = max(t_dyn[t]-t_dyn[t-1], 0), dtL[0] = 0 (matches
  // reference's t_prev init = t_dyn[:,0]). Removes per-step global loads.
  for (int k = tid; k < T_; k += THR) {
    float tk = tdb[k];
    float tp = (k == 0) ? tk : tdb[k - 1];
    dtL[k] = fmaxf(tk - tp, 0.f);
  }

  float b0r = 0.f, b1r = 0.f, b2r = 0.f;
  if (p0 == 0) { b0r = b0[jg0]; b1r = b1[jg0]; }
  if (p2 == 0) b2r = b2[j2];
  const float bhhr = bhh[gcol];
  const float bihr = bih[gcol];
  const int   lenb = lens[b];

  if (tid < 128) {
    float zv = z0[(size_t)b * DZ + tid];
    vinP[cpad(tid)] = zv;
    zcurL[tid] = zv;
  }
  __syncthreads();   // full barrier once, before the loop

  float* Zbase = out + (size_t)B_ * DZ;

  #pragma unroll 1
  for (int t = 0; t < T_; ++t) {
    const size_t bt = (size_t)b * T_ + t;
    const float dt = dtL[t];   // LDS broadcast; covered by first phases

    float gival = 0.f;
    if (use_gi) {
      if (tid < GCOLS) gival = gi_pre[bt * GCOLS + tid];  // lands ~13 barriers later
    } else if (tid < XDIM) {
      float v;
      if (tid < 20)      v = Y[bt * NDYN + tid];
      else if (tid < 40) v = Mm[bt * NDYN + (tid - 20)];
      else               v = Hh[bt * DH + (tid - 40)];
      xsL[tid] = v;
    }

    float zreg = 0.f, kacc = 0.f;
    if (p2 == 0) zreg = zcurL[j2];

    // rolled: 4 RK stages are barrier-serialized anyway; rolling shrinks live
    // ranges / scheduling windows -> keeps peak VGPR pressure moderate.
    #pragma unroll 1
    for (int e = 0; e < 4; ++e) {
      // ---- L0: 64 outs, K=128; 8 threads/out, K-chunk 16 (all 512 lanes) ----
      // read &vinP[p0*20]: word banks tile 0..31 exactly once -> conflict-free
      {
        const float4* vp = (const float4*)&vinP[p0 * 20];
        float a0 = 0.f;
        #pragma unroll
        for (int q = 0; q < 4; ++q) {
          float4 v = vp[q];
          a0 += w0r[4*q+0]*v.x + w0r[4*q+1]*v.y + w0r[4*q+2]*v.z + w0r[4*q+3]*v.w;
        }
        a0 = dpp_sum<0xB1,1>(a0); a0 = dpp_sum<0x4E,2>(a0); a0 = dpp_sum<0x141,4>(a0);
        if (p0 == 0)
          h1P[cpad(jg0)] = tanh_fast(a0 + b0r);
      }
      BAR();
      // ---- L1: 64 outs, K=64; 8 threads/out, K-chunk 8 (all 512 lanes) ----
      // h1[8p0..8p0+7] is contiguous in the padded layout (8p0 mod 16 in {0,8})
      {
        const float4* hp = (const float4*)&h1P[cpad(8 * p0)];
        float4 v0 = hp[0], v1 = hp[1];
        float a0 = w1r[0]*v0.x + w1r[1]*v0.y + w1r[2]*v0.z + w1r[3]*v0.w
                 + w1r[4]*v1.x + w1r[5]*v1.y + w1r[6]*v1.z + w1r[7]*v1.w;
        a0 = dpp_sum<0xB1,1>(a0); a0 = dpp_sum<0x4E,2>(a0); a0 = dpp_sum<0x141,4>(a0);
        if (p0 == 0)
          h2P[cpad(jg0)] = tanh_fast(a0 + b1r);
      }
      BAR();
      // ---- L2: 128 outs, K=64; 4 threads/out, K-chunk 16 (all 512 lanes) ----
      {
        const float4* hp = (const float4*)&h2P[p2 * 20];
        float a0 = 0.f;
        #pragma unroll
        for (int q = 0; q < 4; ++q) {
          float4 v = hp[q];
          a0 += w2r[4*q+0]*v.x + w2r[4*q+1]*v.y + w2r[4*q+2]*v.z + w2r[4*q+3]*v.w;
        }
        a0 = dpp_sum<0xB1,1>(a0); a0 = dpp_sum<0x4E,2>(a0);
        if (p2 == 0) {
          const float kv = dt * (a0 + b2r);
          if (e == 0)      kacc = kv;
          else if (e == 3) kacc += kv;
          else             kacc += 2.f * kv;
          if (e < 3) {
            const float a = (e == 2) ? 1.f : 0.5f;
            vinP[cpad(j2)] = zreg + a * kv;
          } else {
            zodeL[j2] = zreg + kacc * (1.f / 6.f);
          }
        }
      }
      BAR();
    }

    // ---- GRU matvec: column gcol (tid<384). Whh rows 0..67 from LDS
    // (float4-interleaved, 2-deep pipeline), rows 68..127 from registers. ----
    if (tid < GCOLS) {
      float gh0 = bhhr, gh1 = 0.f;
      const float4* zq = (const float4*)zodeL;
      #pragma unroll 1
      for (int g = 0; g < WHH_LDS_G - 1; g += 2) {
        float4 w0 = WhhP4[g * 384 + tid];
        float4 w1 = WhhP4[(g + 1) * 384 + tid];
        float4 za = zq[g];
        float4 zb = zq[g + 1];
        gh0 += w0.x*za.x + w0.y*za.y + w0.z*za.z + w0.w*za.w;
        gh1 += w1.x*zb.x + w1.y*zb.y + w1.z*zb.z + w1.w*zb.w;
      }
      {  // tail group g = 16
        float4 w0 = WhhP4[(WHH_LDS_G - 1) * 384 + tid];
        float4 za = zq[WHH_LDS_G - 1];
        gh0 += w0.x*za.x + w0.y*za.y + w0.z*za.z + w0.w*za.w;
      }
      #pragma unroll   // rows 68..99 (whhA) — compile-time indices (rule #20)
      for (int q = 0; q < 8; ++q) {
        float4 z = zq[WHH_LDS_G + q];
        gh1 += whhA[4*q+0]*z.x + whhA[4*q+1]*z.y + whhA[4*q+2]*z.z + whhA[4*q+3]*z.w;
      }
      #pragma unroll   // rows 100..127 (whhB)
      for (int q = 0; q < 7; ++q) {
        float4 z = zq[WHH_LDS_G + 8 + q];
        gh0 += whhB[4*q+0]*z.x + whhB[4*q+1]*z.y + whhB[4*q+2]*z.z + whhB[4*q+3]*z.w;
      }
      float gh = gh0 + gh1;
      float gi;
      if (use_gi) gi = gival;
      else {
        gi = bihr;
        for (int i = 0; i < XDIM; ++i) gi += xsL[i] * Wih[(size_t)i * GCOLS + tid];
      }
      if (tid < 256) gateL[tid] = gi + gh;
      else { gateL[tid] = gh; gateN[tid - 256] = gi; }
    }
    BAR();

    if (tid < 128) {
      const float r  = sigm(gateL[tid]);
      const float uu = sigm(gateL[128 + tid]);
      const float n  = tanh_fast(gateN[tid] + r * gateL[256 + tid]);
      const float zo = zodeL[tid];
      const float zn = (1.f - uu) * n + uu * zo;
      const float znew = (t < lenb) ? zn : zo;
      vinP[cpad(tid)] = znew;
      zcurL[tid] = znew;
      Zbase[bt * DZ + tid] = znew;
    }
    BAR();
  }

  __syncthreads();
  if (tid < 128) out[(size_t)b * DZ + tid] = zcurL[tid];
}

// ---- pass 1: gi[bt][c] = b_ih[c] + x[bt] @ W_ih  (input-only, fully parallel, fp32)
__global__ __launch_bounds__(384) void gi_precompute(
    const float* __restrict__ Y, const float* __restrict__ Mm,
    const float* __restrict__ Hh, const float* __restrict__ Wih,
    const float* __restrict__ bih, float* __restrict__ gi)
{
  __shared__ float Xs[XDIM][16];
  const int tid = threadIdx.x;
  const size_t bt0 = (size_t)blockIdx.x * 16;
  for (int idx = tid; idx < XDIM * 16; idx += 384) {
    int r = idx & 15, c = idx >> 4;
    size_t bt = bt0 + r;
    float v;
    if (c < 20)      v = Y[bt * NDYN + c];
    else if (c < 40) v = Mm[bt * NDYN + (c - 20)];
    else             v = Hh[bt * DH + (c - 40)];
    Xs[c][r] = v;
  }
  __syncthreads();
  float acc[16];
  const float bv = bih[tid];
  #pragma unroll
  for (int r = 0; r < 16; ++r) acc[r] = bv;
  for (int i = 0; i < XDIM; ++i) {
    float w = Wih[i * GCOLS + tid];
    const float4* xp = (const float4*)(&Xs[i][0]);
    #pragma unroll
    for (int q = 0; q < 4; ++q) {
      float4 xv = xp[q];
      acc[4*q + 0] += xv.x * w;
      acc[4*q + 1] += xv.y * w;
      acc[4*q + 2] += xv.z * w;
      acc[4*q + 3] += xv.w * w;
    }
  }
  #pragma unroll
  for (int r = 0; r < 16; ++r) gi[(bt0 + r) * GCOLS + tid] = acc[r];
}

extern "C" void kernel_launch(void* const* d_in, const int* in_sizes, int n_in,
                              void* d_out, int out_size, void* d_ws, size_t ws_size,
                              hipStream_t stream) {
  const float* z0   = (const float*)d_in[0];
  const float* tdyn = (const float*)d_in[1];
  const float* Y    = (const float*)d_in[2];
  const float* Mm   = (const float*)d_in[3];
  const float* Hh   = (const float*)d_in[4];
  const int*   lens = (const int*)d_in[5];
  const float* W0   = (const float*)d_in[6];
  const float* b0   = (const float*)d_in[7];
  const float* W1   = (const float*)d_in[8];
  const float* b1   = (const float*)d_in[9];
  const float* W2   = (const float*)d_in[10];
  const float* b2   = (const float*)d_in[11];
  const float* Wih  = (const float*)d_in[12];
  const float* bih  = (const float*)d_in[13];
  const float* Whh  = (const float*)d_in[14];
  const float* bhh  = (const float*)d_in[15];
  float* out = (float*)d_out;

  const size_t gi_bytes = (size_t)B_ * T_ * GCOLS * sizeof(float);
  const int use_gi = (ws_size >= gi_bytes) ? 1 : 0;
  float* gi = (float*)d_ws;

  if (use_gi)
    gi_precompute<<<(B_ * T_) / 16, 384, 0, stream>>>(Y, Mm, Hh, Wih, bih, gi);

  odernn_kernel<<<B_, THR, 0, stream>>>(
      z0, tdyn, Y, Mm, Hh, lens, W0, b0, W1, b1, W2, b2,
      Wih, bih, Whh, bhh, use_gi ? gi : nullptr, out, use_gi);
}